// Round 4
// baseline (334.941 us; speedup 1.0000x reference)
//
#include <hip/hip_runtime.h>
#include <math.h>

// Problem constants
#define KCODES 1024
#define DIMV   64
#define NROWS  131072   // 32*64*64
#define HWSZ   4096     // 64*64
#define NELEM  8388608  // 32*64*64*64
#define CAP    224      // rowlist bucket capacity per code
#define CANDCAP 384     // per-block candidate list capacity (64-row blocks)
#define RPB    64       // rows per assign block

// ws layout (bytes):
//   0      : double loss_sum (8) + pad(8)
//   16     : uint wmax_bits (4) + pad(12)
//   32     : int counts[1024]        (4096)     -> memset region [0,4128)
//   4128   : float s_w[1024]         (4096)
//   8224   : ushort WB[65536]        (131072)   bf16 B-fragments
//   139296 : int rowlist[1024*224]   (917504)
// total 1056800 (<= 1073168 known-good)

typedef __attribute__((ext_vector_type(8))) short bf16x8;
typedef __attribute__((ext_vector_type(4))) float f32x4;

static __device__ __forceinline__ unsigned short f2bf(float x) {
    unsigned int u = __float_as_uint(x);
    unsigned int r = (u + 0x7FFFu + ((u >> 16) & 1u)) >> 16;   // RNE
    return (unsigned short)r;
}

// ---- prep: s_w (verbatim pairwise), WB bf16 fragments, wmax ----
__global__ __launch_bounds__(64) void vq_prep3_kernel(
    const float* __restrict__ emb, float* __restrict__ s_w,
    unsigned short* __restrict__ WB, unsigned int* __restrict__ wmax_bits)
{
    int k = blockIdx.x, t = threadIdx.x;
    float v = emb[k * DIMV + t];

    // B-fragment pack: code k = cg*16+n, channel t = kh*32+q*8+j
    {
        int cg = k >> 4, n = k & 15;
        int kh = t >> 5, q = (t & 31) >> 3, j = t & 7;
        WB[((cg * 2 + kh) * 4 + q) * 128 + n * 8 + j] = f2bf(v);
    }

    // wmax via wave max + atomicMax on positive-float bits
    float av = fabsf(v);
    #pragma unroll
    for (int off = 32; off > 0; off >>= 1)
        av = fmaxf(av, __shfl_down(av, off, 64));
    if (t == 0) atomicMax(wmax_bits, __float_as_uint(av));

    // s_w: numpy scalar-pairwise (verbatim)
    __shared__ float sv[64];
    __shared__ float sr[8];
    sv[t] = v;
    __syncthreads();
    if (t < 8) {
        float x = sv[t];
        float sq = x * x;
        asm("" : "+v"(sq));
        float r = sq;
        #pragma unroll
        for (int m = 1; m < 8; ++m) {
            float y = sv[8 * m + t];
            float s2 = y * y;
            asm("" : "+v"(s2));
            r += s2;
        }
        sr[t] = r;
    }
    __syncthreads();
    if (t == 0)
        s_w[k] = ((sr[0] + sr[1]) + (sr[2] + sr[3])) + ((sr[4] + sr[5]) + (sr[6] + sr[7]));
}

// ---- main: MFMA filter + exact recheck + epilogue (flat copy + loss) ----
// 64 rows/block, 8 blocks/CU. tmp_flat aliases q_out; vq_qout_kernel rewrites it.
__global__ __launch_bounds__(256, 8) void vq_assign_kernel(
    const float* __restrict__ inp, const float* __restrict__ emb,
    const unsigned short* __restrict__ WB, const float* __restrict__ s_w,
    const unsigned int* __restrict__ wmax_bits,
    float* __restrict__ tmp_flat, float* __restrict__ enc_out,
    double* __restrict__ loss_sum, int* __restrict__ counts,
    int* __restrict__ rowlist)
{
    __shared__ float At[RPB * 65];            // g=2f fp32, row-major, stride 65 (16640 B)
    __shared__ float sfL[RPB];
    __shared__ float errL[RPB];               // 2*err per row
    __shared__ unsigned long long rowBest[RPB];
    __shared__ int bkL[RPB];
    __shared__ int candL[CANDCAP];
    __shared__ int candCnt;
    // LDS total ~19.5 KB -> 8 blocks/CU

    const int t = threadIdx.x;
    const int n0 = blockIdx.x * RPB;
    const int bq  = n0 >> 12;
    const int hw0 = n0 & 4095;
    const float* fin = inp + (size_t)bq * (DIMV * HWSZ) + hw0;

    if (t < RPB) rowBest[t] = ~0ULL;
    if (t == 0) candCnt = 0;

    // ---- staging: g = 2f -> At (fp32 row-major) ----
    #pragma unroll
    for (int j = 0; j < 4; ++j) {
        int id = j * 256 + t;           // [0,1024)
        int i = id >> 4;                // channel 0..63
        int c4 = id & 15;               // 4-row group 0..15
        float4 v = *(const float4*)(fin + (size_t)i * HWSZ + 4 * c4);
        int r = 4 * c4;
        At[(r + 0) * 65 + i] = v.x + v.x;  At[(r + 1) * 65 + i] = v.y + v.y;
        At[(r + 2) * 65 + i] = v.z + v.z;  At[(r + 3) * 65 + i] = v.w + v.w;
    }
    __syncthreads();

    // ---- sf (verbatim numpy pairwise on f=0.5*g) + errL ----
    if (t < RPB) {
        const float* gr = &At[t * 65];
        float r8[8];
        #pragma unroll
        for (int j = 0; j < 8; ++j) {
            float h = 0.5f * gr[j];
            float sq = h * h;
            asm("" : "+v"(sq));
            r8[j] = sq;
        }
        #pragma unroll
        for (int m = 1; m < 8; ++m) {
            #pragma unroll
            for (int j = 0; j < 8; ++j) {
                float h = 0.5f * gr[8 * m + j];
                float sq = h * h;
                asm("" : "+v"(sq));
                r8[j] += sq;
            }
        }
        sfL[t] = ((r8[0] + r8[1]) + (r8[2] + r8[3])) + ((r8[4] + r8[5]) + (r8[6] + r8[7]));
        float S = 0.0f;
        #pragma unroll
        for (int i = 0; i < 64; ++i) S += fabsf(gr[i]);
        float wmax = __uint_as_float(*wmax_bits);
        errL[t] = fmaf(S * wmax, 0.015625f, 2e-5f);   // 2*err, margin ~1.7x over 2^-6.8
    }
    __syncthreads();

    // ---- MFMA setup: wave wv owns row-group wv (rows 16wv..16wv+15) ----
    const int wv = t >> 6, l = t & 63;
    const int m = l & 15, q = l >> 4;
    bf16x8 a0, a1;
    {
        int row = wv * 16 + m;
        const float* gr = &At[row * 65];
        #pragma unroll
        for (int j = 0; j < 8; ++j) a0[j] = (short)f2bf(gr[q * 8 + j]);
        #pragma unroll
        for (int j = 0; j < 8; ++j) a1[j] = (short)f2bf(gr[32 + q * 8 + j]);
    }

    const unsigned short* wbq = WB + q * 128 + m * 8;
    const float* swm = s_w + m;

    // ---- pass A: per-row min of score' = s_w - g.w (sf dropped: rank-invariant) ----
    float mn[4];
    #pragma unroll
    for (int reg = 0; reg < 4; ++reg) mn[reg] = 3.0e38f;

    {
        bf16x8 pa0 = *(const bf16x8*)(wbq);
        bf16x8 pa1 = *(const bf16x8*)(wbq + 512);
        float   swa = swm[0];
        bf16x8 pb0 = *(const bf16x8*)(wbq + 1024);
        bf16x8 pb1 = *(const bf16x8*)(wbq + 1024 + 512);
        float   swb = swm[16];
        for (int cg = 0; cg < 64; cg += 2) {
            // consume slot A (code-group cg)
            {
                f32x4 acc = {0.f, 0.f, 0.f, 0.f};
                acc = __builtin_amdgcn_mfma_f32_16x16x32_bf16(a0, pa0, acc, 0, 0, 0);
                acc = __builtin_amdgcn_mfma_f32_16x16x32_bf16(a1, pa1, acc, 0, 0, 0);
                #pragma unroll
                for (int reg = 0; reg < 4; ++reg)
                    mn[reg] = fminf(mn[reg], swa - acc[reg]);
            }
            int cna = (cg + 2) & 63;
            pa0 = *(const bf16x8*)(wbq + cna * 1024);
            pa1 = *(const bf16x8*)(wbq + cna * 1024 + 512);
            swa = swm[cna * 16];
            // consume slot B (code-group cg+1)
            {
                f32x4 acc = {0.f, 0.f, 0.f, 0.f};
                acc = __builtin_amdgcn_mfma_f32_16x16x32_bf16(a0, pb0, acc, 0, 0, 0);
                acc = __builtin_amdgcn_mfma_f32_16x16x32_bf16(a1, pb1, acc, 0, 0, 0);
                #pragma unroll
                for (int reg = 0; reg < 4; ++reg)
                    mn[reg] = fminf(mn[reg], swb - acc[reg]);
            }
            int cnb = (cg + 3) & 63;
            pb0 = *(const bf16x8*)(wbq + cnb * 1024);
            pb1 = *(const bf16x8*)(wbq + cnb * 1024 + 512);
            swb = swm[cnb * 16];
        }
    }

    // reduce row minima across the 16 m-lanes holding each row (exact; fmin order-free)
    float th[4];
    #pragma unroll
    for (int reg = 0; reg < 4; ++reg) {
        float v = mn[reg];
        v = fminf(v, __shfl_xor(v, 1, 64));
        v = fminf(v, __shfl_xor(v, 2, 64));
        v = fminf(v, __shfl_xor(v, 4, 64));
        v = fminf(v, __shfl_xor(v, 8, 64));
        th[reg] = v + errL[wv * 16 + q * 4 + reg];
    }

    // ---- pass B: recompute (bit-identical) and collect candidates ----
    {
        bf16x8 pa0 = *(const bf16x8*)(wbq);
        bf16x8 pa1 = *(const bf16x8*)(wbq + 512);
        float   swa = swm[0];
        bf16x8 pb0 = *(const bf16x8*)(wbq + 1024);
        bf16x8 pb1 = *(const bf16x8*)(wbq + 1024 + 512);
        float   swb = swm[16];
        for (int cg = 0; cg < 64; cg += 2) {
            {
                f32x4 acc = {0.f, 0.f, 0.f, 0.f};
                acc = __builtin_amdgcn_mfma_f32_16x16x32_bf16(a0, pa0, acc, 0, 0, 0);
                acc = __builtin_amdgcn_mfma_f32_16x16x32_bf16(a1, pa1, acc, 0, 0, 0);
                #pragma unroll
                for (int reg = 0; reg < 4; ++reg) {
                    if (swa - acc[reg] <= th[reg]) {
                        int row = wv * 16 + q * 4 + reg;
                        int p = atomicAdd(&candCnt, 1);
                        if (p < CANDCAP) candL[p] = (row << 10) | (cg * 16 + m);
                    }
                }
            }
            int cna = (cg + 2) & 63;
            pa0 = *(const bf16x8*)(wbq + cna * 1024);
            pa1 = *(const bf16x8*)(wbq + cna * 1024 + 512);
            swa = swm[cna * 16];
            {
                f32x4 acc = {0.f, 0.f, 0.f, 0.f};
                acc = __builtin_amdgcn_mfma_f32_16x16x32_bf16(a0, pb0, acc, 0, 0, 0);
                acc = __builtin_amdgcn_mfma_f32_16x16x32_bf16(a1, pb1, acc, 0, 0, 0);
                #pragma unroll
                for (int reg = 0; reg < 4; ++reg) {
                    if (swb - acc[reg] <= th[reg]) {
                        int row = wv * 16 + q * 4 + reg;
                        int p = atomicAdd(&candCnt, 1);
                        if (p < CANDCAP) candL[p] = (row << 10) | ((cg + 1) * 16 + m);
                    }
                }
            }
            int cnb = (cg + 3) & 63;
            pb0 = *(const bf16x8*)(wbq + cnb * 1024);
            pb1 = *(const bf16x8*)(wbq + cnb * 1024 + 512);
            swb = swm[cnb * 16];
        }
    }
    __syncthreads();

    // ---- exact recheck of candidates (verbatim sequential fmaf chain) ----
    int nc = candCnt < CANDCAP ? candCnt : CANDCAP;
    for (int c = t; c < nc; c += 256) {
        int pk = candL[c];
        int r = pk >> 10, k = pk & 1023;
        const float* wk = emb + (size_t)k * DIMV;
        const float* gr = &At[r * 65];
        float acc = 0.0f;
        #pragma unroll
        for (int i = 0; i < DIMV; ++i)
            acc = __builtin_fmaf(gr[i], wk[i], acc);
        float d = (sfL[r] - acc) + s_w[k];
        unsigned int u = __float_as_uint(d);
        unsigned int s = (u & 0x80000000u) ? ~u : (u | 0x80000000u);
        unsigned long long key = ((unsigned long long)s << 32) | (unsigned int)k;
        atomicMin(&rowBest[r], key);
    }
    __syncthreads();

    // ---- fallback: no candidate seen OR candidate list overflowed (exact rescan) ----
    if (t < RPB && (rowBest[t] == ~0ULL || candCnt > CANDCAP)) {
        int r = t;
        const float* gr = &At[r * 65];
        float bd = 3.0e38f; int bk = 0;
        for (int k = 0; k < KCODES; ++k) {
            const float* wk = emb + (size_t)k * DIMV;
            float acc = 0.0f;
            #pragma unroll
            for (int i = 0; i < DIMV; ++i)
                acc = __builtin_fmaf(gr[i], wk[i], acc);
            float d = (sfL[r] - acc) + s_w[k];
            if (d < bd) { bd = d; bk = k; }
        }
        unsigned int u = __float_as_uint(bd);
        unsigned int s = (u & 0x80000000u) ? ~u : (u | 0x80000000u);
        rowBest[r] = ((unsigned long long)s << 32) | (unsigned int)bk;
    }
    __syncthreads();

    // ---- selection + place into rowlist ----
    if (t < RPB) {
        int r = t;
        int bk = (int)(rowBest[r] & 1023ULL);
        enc_out[n0 + r] = (float)bk;
        bkL[r] = bk;
        int pos = atomicAdd(&counts[bk], 1);
        if (pos < CAP) rowlist[bk * CAP + pos] = n0 + r;
    }
    __syncthreads();

    // ---- epilogue: flat copy (row-major, coalesced) + loss ----
    float* tq = tmp_flat + (size_t)n0 * DIMV;
    double lsum = 0.0;
    #pragma unroll
    for (int j = 0; j < 16; ++j) {
        int idx = j * 256 + t;
        int r = idx >> 6;          // row 0..63 (one row per 64-lane group)
        int i = idx & 63;          // channel
        int bk = bkL[r];
        float fi = 0.5f * At[r * 65 + i];
        tq[r * DIMV + i] = fi;                       // coalesced 256B/group
        float qv = emb[bk * DIMV + i];               // contiguous 256B/group
        double dq = (double)qv - (double)fi;
        lsum = fma(dq, dq, lsum);
    }
    #pragma unroll
    for (int off = 32; off > 0; off >>= 1)
        lsum += __shfl_down(lsum, off, 64);
    if ((t & 63) == 0) atomicAdd(loss_sum, lsum);
}

// ---- tail: nsum -> adj/ncs, dw gather from row-major flat copy, loss ----
__global__ __launch_bounds__(256) void vq_dw_all_kernel(
    const float* __restrict__ tmp_flat, const int* __restrict__ rowlist,
    const int* __restrict__ counts, const float* __restrict__ ema_cs,
    const float* __restrict__ ema_w, const double* __restrict__ loss_sum,
    float* __restrict__ out_loss, float* __restrict__ out_nll,
    float* __restrict__ out_ncs, float* __restrict__ out_nema,
    float* __restrict__ out_nemb)
{
    const int k = blockIdx.x;
    const int t = threadIdx.x;
    const double DECAY = 0.99;
    const double OMD   = 1.0 - 0.99;
    const double EPSV  = 1e-5;

    __shared__ double sm[256];
    double part = 0.0;
    #pragma unroll
    for (int j0 = 0; j0 < 4; ++j0) {
        int j = j0 * 256 + t;
        part += (double)ema_cs[j] * DECAY + OMD * (double)counts[j];
    }
    sm[t] = part;
    __syncthreads();
    #pragma unroll
    for (int off = 128; off > 0; off >>= 1) {
        if (t < off) sm[t] += sm[t + off];
        __syncthreads();
    }
    double nsum = sm[0];

    int cnt = counts[k];
    double ncs = (double)ema_cs[k] * DECAY + OMD * (double)cnt;
    double adj = (ncs + EPSV) / (nsum + (double)KCODES * EPSV) * nsum;
    if (t == 0) out_ncs[k] = (float)adj;
    if (k == 0 && t == 0) {
        double e = loss_sum[0] / (double)NELEM;
        out_loss[0] = (float)(e + 0.25 * e);
        out_nll[0]  = 1.0f;
    }

    int i = t & 63;
    int sub = t >> 6;
    int cap = cnt < CAP ? cnt : CAP;

    float acc = 0.0f;
    #pragma unroll 4
    for (int r = sub; r < cap; r += 4) {
        int n = rowlist[k * CAP + r];
        acc += tmp_flat[(size_t)n * DIMV + i];       // 256B contiguous per row
    }

    __shared__ float red[256];
    red[t] = acc;
    __syncthreads();
    if (t < 128) red[t] += red[t + 128];
    __syncthreads();
    if (t < 64) {
        float dwv = red[t] + red[t + 64];
        int idx = k * DIMV + i;
        double ne = (double)ema_w[idx] * DECAY + OMD * (double)dwv;
        out_nema[idx] = (float)ne;
        out_nemb[idx] = (float)(ne / adj);
    }
}

// ---- final: overwrite q_out region (NCHW) from enc + emb ----
__global__ __launch_bounds__(256) void vq_qout_kernel(
    const float* __restrict__ enc, const float* __restrict__ emb,
    float* __restrict__ q_out)
{
    __shared__ int bkL[128];
    const int t = threadIdx.x;
    const int n0 = blockIdx.x * 128;
    const int bq  = n0 >> 12;
    const int hw0 = n0 & 4095;
    if (t < 128) bkL[t] = (int)enc[n0 + t];
    __syncthreads();
    float* qo = q_out + (size_t)bq * (DIMV * HWSZ) + hw0;
    #pragma unroll
    for (int j = 0; j < 32; ++j) {
        int idx = j * 256 + t;
        int r = idx & 127;
        int i = idx >> 7;
        qo[(size_t)i * HWSZ + r] = emb[bkL[r] * DIMV + i];
    }
}

extern "C" void kernel_launch(void* const* d_in, const int* in_sizes, int n_in,
                              void* d_out, int out_size, void* d_ws, size_t ws_size,
                              hipStream_t stream) {
    const float* inp    = (const float*)d_in[0];  // (32,64,64,64) NCHW
    const float* emb    = (const float*)d_in[1];  // (1024,64)
    const float* ema_cs = (const float*)d_in[2];  // (1024,)
    const float* ema_w  = (const float*)d_in[3];  // (1024,64)

    char* ws = (char*)d_ws;
    double*         loss_sum  = (double*)(ws + 0);
    unsigned int*   wmax_bits = (unsigned int*)(ws + 16);
    int*            counts    = (int*)(ws + 32);
    float*          s_w       = (float*)(ws + 4128);
    unsigned short* WB        = (unsigned short*)(ws + 8224);
    int*            rowlist   = (int*)(ws + 139296);

    float* out       = (float*)d_out;
    float* q_out     = out;                       // 8388608 (holds flat copy until vq_qout)
    float* enc_out   = out + 8388608;             // 131072
    float* out_loss  = out + 8519680;             // 1
    float* out_nll   = out + 8519681;             // 1
    float* out_ncs   = out + 8519682;             // 1024
    float* out_nema  = out + 8520706;             // 65536
    float* out_nemb  = out + 8586242;             // 65536

    hipMemsetAsync(ws, 0, 4128, stream);   // loss_sum + wmax + counts
    hipLaunchKernelGGL(vq_prep3_kernel, dim3(KCODES), dim3(64), 0, stream,
                       emb, s_w, WB, wmax_bits);
    hipLaunchKernelGGL(vq_assign_kernel, dim3(NROWS / RPB), dim3(256), 0, stream,
                       inp, emb, WB, s_w, wmax_bits,
                       q_out /*tmp_flat*/, enc_out, loss_sum, counts, rowlist);
    hipLaunchKernelGGL(vq_dw_all_kernel, dim3(KCODES), dim3(256), 0, stream,
                       q_out /*tmp_flat*/, rowlist, counts, ema_cs, ema_w, loss_sum,
                       out_loss, out_nll, out_ncs, out_nema, out_nemb);
    hipLaunchKernelGGL(vq_qout_kernel, dim3(NROWS / 128), dim3(256), 0, stream,
                       enc_out, emb, q_out);
}

// Round 5
// 249.806 us; speedup vs baseline: 1.3408x; 1.3408x over previous
//
#include <hip/hip_runtime.h>
#include <math.h>

// Problem constants
#define KCODES 1024
#define DIMV   64
#define NROWS  131072   // 32*64*64
#define HWSZ   4096     // 64*64
#define NELEM  8388608  // 32*64*64*64
#define CAP    224      // rowlist bucket capacity per code
#define CANDCAP 1024    // per-block candidate list capacity
#define RPB    128      // rows per assign block

// ws layout (bytes):
//   0      : double loss_sum (8) + pad(8)
//   16     : uint wmax_bits (4) + pad(12)
//   32     : int counts[1024]        (4096)     -> memset region [0,4128)
//   4128   : float s_w[1024]         (4096)
//   8224   : ushort WB[65536]        (131072)   bf16 B-fragments
//   139296 : int rowlist[1024*224]   (917504)
// total 1056800 (<= 1073168 known-good)

typedef __attribute__((ext_vector_type(8))) short bf16x8;
typedef __attribute__((ext_vector_type(4))) float f32x4;

static __device__ __forceinline__ unsigned short f2bf(float x) {
    unsigned int u = __float_as_uint(x);
    unsigned int r = (u + 0x7FFFu + ((u >> 16) & 1u)) >> 16;   // RNE
    return (unsigned short)r;
}

// ---- prep: s_w (verbatim pairwise), WB bf16 fragments, wmax ----
__global__ __launch_bounds__(64) void vq_prep3_kernel(
    const float* __restrict__ emb, float* __restrict__ s_w,
    unsigned short* __restrict__ WB, unsigned int* __restrict__ wmax_bits)
{
    int k = blockIdx.x, t = threadIdx.x;
    float v = emb[k * DIMV + t];

    // B-fragment pack: code k = cg*16+n, channel t = kh*32+q*8+j
    {
        int cg = k >> 4, n = k & 15;
        int kh = t >> 5, q = (t & 31) >> 3, j = t & 7;
        WB[((cg * 2 + kh) * 4 + q) * 128 + n * 8 + j] = f2bf(v);
    }

    // wmax via wave max + atomicMax on positive-float bits
    float av = fabsf(v);
    #pragma unroll
    for (int off = 32; off > 0; off >>= 1)
        av = fmaxf(av, __shfl_down(av, off, 64));
    if (t == 0) atomicMax(wmax_bits, __float_as_uint(av));

    // s_w: numpy scalar-pairwise (verbatim)
    __shared__ float sv[64];
    __shared__ float sr[8];
    sv[t] = v;
    __syncthreads();
    if (t < 8) {
        float x = sv[t];
        float sq = x * x;
        asm("" : "+v"(sq));
        float r = sq;
        #pragma unroll
        for (int m = 1; m < 8; ++m) {
            float y = sv[8 * m + t];
            float s2 = y * y;
            asm("" : "+v"(s2));
            r += s2;
        }
        sr[t] = r;
    }
    __syncthreads();
    if (t == 0)
        s_w[k] = ((sr[0] + sr[1]) + (sr[2] + sr[3])) + ((sr[4] + sr[5]) + (sr[6] + sr[7]));
}

// ---- main: MFMA filter + exact recheck + epilogue (flat copy + loss) ----
// 128 rows/block, 4 blocks/CU, 4-deep register prefetch of WB.
__global__ __launch_bounds__(256, 4) void vq_assign_kernel(
    const float* __restrict__ inp, const float* __restrict__ emb,
    const unsigned short* __restrict__ WB, const float* __restrict__ s_w,
    const unsigned int* __restrict__ wmax_bits,
    float* __restrict__ tmp_flat, float* __restrict__ enc_out,
    double* __restrict__ loss_sum, int* __restrict__ counts,
    int* __restrict__ rowlist)
{
    __shared__ float At[RPB * 65];            // g=2f fp32, row-major, stride 65
    __shared__ float sfL[RPB];
    __shared__ float errL[RPB];               // 2*err per row
    __shared__ unsigned long long rowBest[RPB];
    __shared__ int bkL[RPB];
    __shared__ int candL[CANDCAP];
    __shared__ int candCnt;
    // LDS total ~39.9 KB -> 4 blocks/CU

    const int t = threadIdx.x;
    const int n0 = blockIdx.x * RPB;
    const int bq  = n0 >> 12;
    const int hw0 = n0 & 4095;
    const float* fin = inp + (size_t)bq * (DIMV * HWSZ) + hw0;

    if (t < RPB) rowBest[t] = ~0ULL;
    if (t == 0) candCnt = 0;

    // ---- staging: g = 2f -> At (fp32 row-major) ----
    #pragma unroll
    for (int j = 0; j < 8; ++j) {
        int id = j * 256 + t;           // [0,2048)
        int i = id >> 5;                // channel
        int c4 = id & 31;               // 4-row group
        float4 v = *(const float4*)(fin + (size_t)i * HWSZ + 4 * c4);
        int r = 4 * c4;
        At[(r + 0) * 65 + i] = v.x + v.x;  At[(r + 1) * 65 + i] = v.y + v.y;
        At[(r + 2) * 65 + i] = v.z + v.z;  At[(r + 3) * 65 + i] = v.w + v.w;
    }
    __syncthreads();

    // ---- sf (verbatim numpy pairwise on f=0.5*g) + errL ----
    if (t < RPB) {
        const float* gr = &At[t * 65];
        float r8[8];
        #pragma unroll
        for (int j = 0; j < 8; ++j) {
            float h = 0.5f * gr[j];
            float sq = h * h;
            asm("" : "+v"(sq));
            r8[j] = sq;
        }
        #pragma unroll
        for (int m = 1; m < 8; ++m) {
            #pragma unroll
            for (int j = 0; j < 8; ++j) {
                float h = 0.5f * gr[8 * m + j];
                float sq = h * h;
                asm("" : "+v"(sq));
                r8[j] += sq;
            }
        }
        sfL[t] = ((r8[0] + r8[1]) + (r8[2] + r8[3])) + ((r8[4] + r8[5]) + (r8[6] + r8[7]));
        float S = 0.0f;
        #pragma unroll
        for (int i = 0; i < 64; ++i) S += fabsf(gr[i]);
        float wmax = __uint_as_float(*wmax_bits);
        errL[t] = fmaf(S * wmax, 0.015625f, 2e-5f);   // 2*err, margin ~1.7x over 2^-6.8
    }
    __syncthreads();

    // ---- MFMA setup: wave wv owns row-groups {2wv, 2wv+1} ----
    const int wv = t >> 6, l = t & 63;
    const int m = l & 15, q = l >> 4;
    bf16x8 afr[2][2];
    float erf[2][4];
    #pragma unroll
    for (int rg2 = 0; rg2 < 2; ++rg2) {
        int row = (2 * wv + rg2) * 16 + m;
        const float* gr = &At[row * 65];
        #pragma unroll
        for (int kh = 0; kh < 2; ++kh) {
            bf16x8 a;
            #pragma unroll
            for (int j = 0; j < 8; ++j)
                a[j] = (short)f2bf(gr[kh * 32 + q * 8 + j]);
            afr[rg2][kh] = a;
        }
        #pragma unroll
        for (int reg = 0; reg < 4; ++reg)
            erf[rg2][reg] = errL[(2 * wv + rg2) * 16 + q * 4 + reg];
    }

    const unsigned short* wbq = WB + q * 128 + m * 8;
    const float* swm = s_w + m;

    // ---- pass A: per-row min of score' = s_w - g.w (sf dropped: rank-invariant) ----
    float mn[2][4];
    #pragma unroll
    for (int rg2 = 0; rg2 < 2; ++rg2)
        #pragma unroll
        for (int reg = 0; reg < 4; ++reg) mn[rg2][reg] = 3.0e38f;

    {
        bf16x8 pa0 = *(const bf16x8*)(wbq + 0 * 1024);
        bf16x8 pa1 = *(const bf16x8*)(wbq + 0 * 1024 + 512);
        float   swa = swm[0 * 16];
        bf16x8 pb0 = *(const bf16x8*)(wbq + 1 * 1024);
        bf16x8 pb1 = *(const bf16x8*)(wbq + 1 * 1024 + 512);
        float   swb = swm[1 * 16];
        bf16x8 pc0 = *(const bf16x8*)(wbq + 2 * 1024);
        bf16x8 pc1 = *(const bf16x8*)(wbq + 2 * 1024 + 512);
        float   swc = swm[2 * 16];
        bf16x8 pd0 = *(const bf16x8*)(wbq + 3 * 1024);
        bf16x8 pd1 = *(const bf16x8*)(wbq + 3 * 1024 + 512);
        float   swd = swm[3 * 16];
        for (int cg = 0; cg < 64; cg += 4) {
            // consume slot A (cg)
            #pragma unroll
            for (int rg2 = 0; rg2 < 2; ++rg2) {
                f32x4 acc = {0.f, 0.f, 0.f, 0.f};
                acc = __builtin_amdgcn_mfma_f32_16x16x32_bf16(afr[rg2][0], pa0, acc, 0, 0, 0);
                acc = __builtin_amdgcn_mfma_f32_16x16x32_bf16(afr[rg2][1], pa1, acc, 0, 0, 0);
                #pragma unroll
                for (int reg = 0; reg < 4; ++reg)
                    mn[rg2][reg] = fminf(mn[rg2][reg], swa - acc[reg]);
            }
            {
                int cn = (cg + 4) & 63;
                pa0 = *(const bf16x8*)(wbq + cn * 1024);
                pa1 = *(const bf16x8*)(wbq + cn * 1024 + 512);
                swa = swm[cn * 16];
            }
            // consume slot B (cg+1)
            #pragma unroll
            for (int rg2 = 0; rg2 < 2; ++rg2) {
                f32x4 acc = {0.f, 0.f, 0.f, 0.f};
                acc = __builtin_amdgcn_mfma_f32_16x16x32_bf16(afr[rg2][0], pb0, acc, 0, 0, 0);
                acc = __builtin_amdgcn_mfma_f32_16x16x32_bf16(afr[rg2][1], pb1, acc, 0, 0, 0);
                #pragma unroll
                for (int reg = 0; reg < 4; ++reg)
                    mn[rg2][reg] = fminf(mn[rg2][reg], swb - acc[reg]);
            }
            {
                int cn = (cg + 5) & 63;
                pb0 = *(const bf16x8*)(wbq + cn * 1024);
                pb1 = *(const bf16x8*)(wbq + cn * 1024 + 512);
                swb = swm[cn * 16];
            }
            // consume slot C (cg+2)
            #pragma unroll
            for (int rg2 = 0; rg2 < 2; ++rg2) {
                f32x4 acc = {0.f, 0.f, 0.f, 0.f};
                acc = __builtin_amdgcn_mfma_f32_16x16x32_bf16(afr[rg2][0], pc0, acc, 0, 0, 0);
                acc = __builtin_amdgcn_mfma_f32_16x16x32_bf16(afr[rg2][1], pc1, acc, 0, 0, 0);
                #pragma unroll
                for (int reg = 0; reg < 4; ++reg)
                    mn[rg2][reg] = fminf(mn[rg2][reg], swc - acc[reg]);
            }
            {
                int cn = (cg + 6) & 63;
                pc0 = *(const bf16x8*)(wbq + cn * 1024);
                pc1 = *(const bf16x8*)(wbq + cn * 1024 + 512);
                swc = swm[cn * 16];
            }
            // consume slot D (cg+3)
            #pragma unroll
            for (int rg2 = 0; rg2 < 2; ++rg2) {
                f32x4 acc = {0.f, 0.f, 0.f, 0.f};
                acc = __builtin_amdgcn_mfma_f32_16x16x32_bf16(afr[rg2][0], pd0, acc, 0, 0, 0);
                acc = __builtin_amdgcn_mfma_f32_16x16x32_bf16(afr[rg2][1], pd1, acc, 0, 0, 0);
                #pragma unroll
                for (int reg = 0; reg < 4; ++reg)
                    mn[rg2][reg] = fminf(mn[rg2][reg], swd - acc[reg]);
            }
            {
                int cn = (cg + 7) & 63;
                pd0 = *(const bf16x8*)(wbq + cn * 1024);
                pd1 = *(const bf16x8*)(wbq + cn * 1024 + 512);
                swd = swm[cn * 16];
            }
        }
    }

    // reduce row minima across the 16 m-lanes holding each row (exact; fmin order-free)
    float th[2][4];
    #pragma unroll
    for (int rg2 = 0; rg2 < 2; ++rg2)
        #pragma unroll
        for (int reg = 0; reg < 4; ++reg) {
            float v = mn[rg2][reg];
            v = fminf(v, __shfl_xor(v, 1, 64));
            v = fminf(v, __shfl_xor(v, 2, 64));
            v = fminf(v, __shfl_xor(v, 4, 64));
            v = fminf(v, __shfl_xor(v, 8, 64));
            th[rg2][reg] = v + erf[rg2][reg];
        }

    // ---- pass B: recompute (bit-identical) and collect candidates ----
    {
        bf16x8 pa0 = *(const bf16x8*)(wbq + 0 * 1024);
        bf16x8 pa1 = *(const bf16x8*)(wbq + 0 * 1024 + 512);
        float   swa = swm[0 * 16];
        bf16x8 pb0 = *(const bf16x8*)(wbq + 1 * 1024);
        bf16x8 pb1 = *(const bf16x8*)(wbq + 1 * 1024 + 512);
        float   swb = swm[1 * 16];
        bf16x8 pc0 = *(const bf16x8*)(wbq + 2 * 1024);
        bf16x8 pc1 = *(const bf16x8*)(wbq + 2 * 1024 + 512);
        float   swc = swm[2 * 16];
        bf16x8 pd0 = *(const bf16x8*)(wbq + 3 * 1024);
        bf16x8 pd1 = *(const bf16x8*)(wbq + 3 * 1024 + 512);
        float   swd = swm[3 * 16];
        for (int cg = 0; cg < 64; cg += 4) {
            // consume slot A (cg)
            #pragma unroll
            for (int rg2 = 0; rg2 < 2; ++rg2) {
                f32x4 acc = {0.f, 0.f, 0.f, 0.f};
                acc = __builtin_amdgcn_mfma_f32_16x16x32_bf16(afr[rg2][0], pa0, acc, 0, 0, 0);
                acc = __builtin_amdgcn_mfma_f32_16x16x32_bf16(afr[rg2][1], pa1, acc, 0, 0, 0);
                #pragma unroll
                for (int reg = 0; reg < 4; ++reg) {
                    if (swa - acc[reg] <= th[rg2][reg]) {
                        int row = (2 * wv + rg2) * 16 + q * 4 + reg;
                        int p = atomicAdd(&candCnt, 1);
                        if (p < CANDCAP) candL[p] = (row << 10) | (cg * 16 + m);
                    }
                }
            }
            {
                int cn = (cg + 4) & 63;
                pa0 = *(const bf16x8*)(wbq + cn * 1024);
                pa1 = *(const bf16x8*)(wbq + cn * 1024 + 512);
                swa = swm[cn * 16];
            }
            // consume slot B (cg+1)
            #pragma unroll
            for (int rg2 = 0; rg2 < 2; ++rg2) {
                f32x4 acc = {0.f, 0.f, 0.f, 0.f};
                acc = __builtin_amdgcn_mfma_f32_16x16x32_bf16(afr[rg2][0], pb0, acc, 0, 0, 0);
                acc = __builtin_amdgcn_mfma_f32_16x16x32_bf16(afr[rg2][1], pb1, acc, 0, 0, 0);
                #pragma unroll
                for (int reg = 0; reg < 4; ++reg) {
                    if (swb - acc[reg] <= th[rg2][reg]) {
                        int row = (2 * wv + rg2) * 16 + q * 4 + reg;
                        int p = atomicAdd(&candCnt, 1);
                        if (p < CANDCAP) candL[p] = (row << 10) | ((cg + 1) * 16 + m);
                    }
                }
            }
            {
                int cn = (cg + 5) & 63;
                pb0 = *(const bf16x8*)(wbq + cn * 1024);
                pb1 = *(const bf16x8*)(wbq + cn * 1024 + 512);
                swb = swm[cn * 16];
            }
            // consume slot C (cg+2)
            #pragma unroll
            for (int rg2 = 0; rg2 < 2; ++rg2) {
                f32x4 acc = {0.f, 0.f, 0.f, 0.f};
                acc = __builtin_amdgcn_mfma_f32_16x16x32_bf16(afr[rg2][0], pc0, acc, 0, 0, 0);
                acc = __builtin_amdgcn_mfma_f32_16x16x32_bf16(afr[rg2][1], pc1, acc, 0, 0, 0);
                #pragma unroll
                for (int reg = 0; reg < 4; ++reg) {
                    if (swc - acc[reg] <= th[rg2][reg]) {
                        int row = (2 * wv + rg2) * 16 + q * 4 + reg;
                        int p = atomicAdd(&candCnt, 1);
                        if (p < CANDCAP) candL[p] = (row << 10) | ((cg + 2) * 16 + m);
                    }
                }
            }
            {
                int cn = (cg + 6) & 63;
                pc0 = *(const bf16x8*)(wbq + cn * 1024);
                pc1 = *(const bf16x8*)(wbq + cn * 1024 + 512);
                swc = swm[cn * 16];
            }
            // consume slot D (cg+3)
            #pragma unroll
            for (int rg2 = 0; rg2 < 2; ++rg2) {
                f32x4 acc = {0.f, 0.f, 0.f, 0.f};
                acc = __builtin_amdgcn_mfma_f32_16x16x32_bf16(afr[rg2][0], pd0, acc, 0, 0, 0);
                acc = __builtin_amdgcn_mfma_f32_16x16x32_bf16(afr[rg2][1], pd1, acc, 0, 0, 0);
                #pragma unroll
                for (int reg = 0; reg < 4; ++reg) {
                    if (swd - acc[reg] <= th[rg2][reg]) {
                        int row = (2 * wv + rg2) * 16 + q * 4 + reg;
                        int p = atomicAdd(&candCnt, 1);
                        if (p < CANDCAP) candL[p] = (row << 10) | ((cg + 3) * 16 + m);
                    }
                }
            }
            {
                int cn = (cg + 7) & 63;
                pd0 = *(const bf16x8*)(wbq + cn * 1024);
                pd1 = *(const bf16x8*)(wbq + cn * 1024 + 512);
                swd = swm[cn * 16];
            }
        }
    }
    __syncthreads();

    // ---- exact recheck of candidates (verbatim sequential fmaf chain) ----
    int nc = candCnt < CANDCAP ? candCnt : CANDCAP;
    for (int c = t; c < nc; c += 256) {
        int pk = candL[c];
        int r = pk >> 10, k = pk & 1023;
        const float* wk = emb + (size_t)k * DIMV;
        const float* gr = &At[r * 65];
        float acc = 0.0f;
        #pragma unroll
        for (int i = 0; i < DIMV; ++i)
            acc = __builtin_fmaf(gr[i], wk[i], acc);
        float d = (sfL[r] - acc) + s_w[k];
        unsigned int u = __float_as_uint(d);
        unsigned int s = (u & 0x80000000u) ? ~u : (u | 0x80000000u);
        unsigned long long key = ((unsigned long long)s << 32) | (unsigned int)k;
        atomicMin(&rowBest[r], key);
    }
    __syncthreads();

    // ---- fallback: no candidate seen OR candidate list overflowed (exact rescan) ----
    if (t < RPB && (rowBest[t] == ~0ULL || candCnt > CANDCAP)) {
        int r = t;
        const float* gr = &At[r * 65];
        float bd = 3.0e38f; int bk = 0;
        for (int k = 0; k < KCODES; ++k) {
            const float* wk = emb + (size_t)k * DIMV;
            float acc = 0.0f;
            #pragma unroll
            for (int i = 0; i < DIMV; ++i)
                acc = __builtin_fmaf(gr[i], wk[i], acc);
            float d = (sfL[r] - acc) + s_w[k];
            if (d < bd) { bd = d; bk = k; }
        }
        unsigned int u = __float_as_uint(bd);
        unsigned int s = (u & 0x80000000u) ? ~u : (u | 0x80000000u);
        rowBest[r] = ((unsigned long long)s << 32) | (unsigned int)bk;
    }
    __syncthreads();

    // ---- selection + place into rowlist ----
    if (t < RPB) {
        int r = t;
        int bk = (int)(rowBest[r] & 1023ULL);
        enc_out[n0 + r] = (float)bk;
        bkL[r] = bk;
        int pos = atomicAdd(&counts[bk], 1);
        if (pos < CAP) rowlist[bk * CAP + pos] = n0 + r;
    }
    __syncthreads();

    // ---- epilogue: flat copy (row-major, coalesced) + loss ----
    float* tq = tmp_flat + (size_t)n0 * DIMV;
    double lsum = 0.0;
    #pragma unroll
    for (int j = 0; j < 32; ++j) {
        int idx = j * 256 + t;
        int r = idx >> 6;          // row 0..127 (one row per 64-lane group)
        int i = idx & 63;          // channel
        int bk = bkL[r];
        float fi = 0.5f * At[r * 65 + i];
        tq[r * DIMV + i] = fi;                       // coalesced 256B/group
        float qv = emb[bk * DIMV + i];               // contiguous 256B/group
        double dq = (double)qv - (double)fi;
        lsum = fma(dq, dq, lsum);
    }
    #pragma unroll
    for (int off = 32; off > 0; off >>= 1)
        lsum += __shfl_down(lsum, off, 64);
    if ((t & 63) == 0) atomicAdd(loss_sum, lsum);
}

// ---- tail: nsum -> adj/ncs, dw gather from row-major flat copy, loss ----
__global__ __launch_bounds__(256) void vq_dw_all_kernel(
    const float* __restrict__ tmp_flat, const int* __restrict__ rowlist,
    const int* __restrict__ counts, const float* __restrict__ ema_cs,
    const float* __restrict__ ema_w, const double* __restrict__ loss_sum,
    float* __restrict__ out_loss, float* __restrict__ out_nll,
    float* __restrict__ out_ncs, float* __restrict__ out_nema,
    float* __restrict__ out_nemb)
{
    const int k = blockIdx.x;
    const int t = threadIdx.x;
    const double DECAY = 0.99;
    const double OMD   = 1.0 - 0.99;
    const double EPSV  = 1e-5;

    __shared__ double sm[256];
    double part = 0.0;
    #pragma unroll
    for (int j0 = 0; j0 < 4; ++j0) {
        int j = j0 * 256 + t;
        part += (double)ema_cs[j] * DECAY + OMD * (double)counts[j];
    }
    sm[t] = part;
    __syncthreads();
    #pragma unroll
    for (int off = 128; off > 0; off >>= 1) {
        if (t < off) sm[t] += sm[t + off];
        __syncthreads();
    }
    double nsum = sm[0];

    int cnt = counts[k];
    double ncs = (double)ema_cs[k] * DECAY + OMD * (double)cnt;
    double adj = (ncs + EPSV) / (nsum + (double)KCODES * EPSV) * nsum;
    if (t == 0) out_ncs[k] = (float)adj;
    if (k == 0 && t == 0) {
        double e = loss_sum[0] / (double)NELEM;
        out_loss[0] = (float)(e + 0.25 * e);
        out_nll[0]  = 1.0f;
    }

    int i = t & 63;
    int sub = t >> 6;
    int cap = cnt < CAP ? cnt : CAP;

    float acc = 0.0f;
    #pragma unroll 4
    for (int r = sub; r < cap; r += 4) {
        int n = rowlist[k * CAP + r];
        acc += tmp_flat[(size_t)n * DIMV + i];       // 256B contiguous per row
    }

    __shared__ float red[256];
    red[t] = acc;
    __syncthreads();
    if (t < 128) red[t] += red[t + 128];
    __syncthreads();
    if (t < 64) {
        float dwv = red[t] + red[t + 64];
        int idx = k * DIMV + i;
        double ne = (double)ema_w[idx] * DECAY + OMD * (double)dwv;
        out_nema[idx] = (float)ne;
        out_nemb[idx] = (float)(ne / adj);
    }
}

// ---- final: overwrite q_out region (NCHW) from enc + emb ----
__global__ __launch_bounds__(256) void vq_qout_kernel(
    const float* __restrict__ enc, const float* __restrict__ emb,
    float* __restrict__ q_out)
{
    __shared__ int bkL[128];
    const int t = threadIdx.x;
    const int n0 = blockIdx.x * 128;
    const int bq  = n0 >> 12;
    const int hw0 = n0 & 4095;
    if (t < 128) bkL[t] = (int)enc[n0 + t];
    __syncthreads();
    float* qo = q_out + (size_t)bq * (DIMV * HWSZ) + hw0;
    #pragma unroll
    for (int j = 0; j < 32; ++j) {
        int idx = j * 256 + t;
        int r = idx & 127;
        int i = idx >> 7;
        qo[(size_t)i * HWSZ + r] = emb[bkL[r] * DIMV + i];
    }
}

extern "C" void kernel_launch(void* const* d_in, const int* in_sizes, int n_in,
                              void* d_out, int out_size, void* d_ws, size_t ws_size,
                              hipStream_t stream) {
    const float* inp    = (const float*)d_in[0];  // (32,64,64,64) NCHW
    const float* emb    = (const float*)d_in[1];  // (1024,64)
    const float* ema_cs = (const float*)d_in[2];  // (1024,)
    const float* ema_w  = (const float*)d_in[3];  // (1024,64)

    char* ws = (char*)d_ws;
    double*         loss_sum  = (double*)(ws + 0);
    unsigned int*   wmax_bits = (unsigned int*)(ws + 16);
    int*            counts    = (int*)(ws + 32);
    float*          s_w       = (float*)(ws + 4128);
    unsigned short* WB        = (unsigned short*)(ws + 8224);
    int*            rowlist   = (int*)(ws + 139296);

    float* out       = (float*)d_out;
    float* q_out     = out;                       // 8388608 (holds flat copy until vq_qout)
    float* enc_out   = out + 8388608;             // 131072
    float* out_loss  = out + 8519680;             // 1
    float* out_nll   = out + 8519681;             // 1
    float* out_ncs   = out + 8519682;             // 1024
    float* out_nema  = out + 8520706;             // 65536
    float* out_nemb  = out + 8586242;             // 65536

    hipMemsetAsync(ws, 0, 4128, stream);   // loss_sum + wmax + counts
    hipLaunchKernelGGL(vq_prep3_kernel, dim3(KCODES), dim3(64), 0, stream,
                       emb, s_w, WB, wmax_bits);
    hipLaunchKernelGGL(vq_assign_kernel, dim3(NROWS / RPB), dim3(256), 0, stream,
                       inp, emb, WB, s_w, wmax_bits,
                       q_out /*tmp_flat*/, enc_out, loss_sum, counts, rowlist);
    hipLaunchKernelGGL(vq_dw_all_kernel, dim3(KCODES), dim3(256), 0, stream,
                       q_out /*tmp_flat*/, rowlist, counts, ema_cs, ema_w, loss_sum,
                       out_loss, out_nll, out_ncs, out_nema, out_nemb);
    hipLaunchKernelGGL(vq_qout_kernel, dim3(NROWS / 128), dim3(256), 0, stream,
                       enc_out, emb, q_out);
}